// Round 7
// baseline (151.986 us; speedup 1.0000x reference)
//
#include <hip/hip_runtime.h>
#include <math.h>

// Problem constants
#define NB    16            // batches
#define NPB   (512*512)     // elements per batch
#define NBINS 64
#define MMB   16            // minmax blocks per batch
#define CB    64            // hist chunks per (tensor,batch) -> grid 2*16*64 = 2048
#define EPSF  1e-8f
#define QF    0.84932180517f   // sqrt(0.5*log2(e)); exp(-d^2/2) = exp2(-(q*d)^2)
#define L2E   1.44269504089f   // log2(e)
#define C1    0.36787944117f   // e^-1
#define C3    0.04978706837f   // e^-3
#define C4    0.01831563889f   // e^-4
#define LN2   0.69314718056f

typedef float v2f __attribute__((ext_vector_type(2)));

// ws layout: mmn[256] | mmx[256] | hist[2][16][64] | done(uint)

// ---------- pass 1: per-batch block-level min/max (also zeroes hist + done) ----------
__global__ __launch_bounds__(256) void minmax_k(const float4* __restrict__ tgt,
                                                float* __restrict__ mmn,
                                                float* __restrict__ mmx,
                                                float* __restrict__ hist,
                                                unsigned* __restrict__ done) {
    const int batch = blockIdx.x >> 4, sub = blockIdx.x & 15;
    if (sub == 0 && threadIdx.x < 128) {
        const int tens = threadIdx.x >> 6, lane = threadIdx.x & 63;
        hist[(tens * NB + batch) * NBINS + lane] = 0.0f;
    }
    if (blockIdx.x == 0 && threadIdx.x == 0) *done = 0u;

    const int F4 = NPB / 4 / MMB;              // 4096 float4 per block
    const float4* p = tgt + (size_t)batch * (NPB / 4) + (size_t)sub * F4;
    float mn = 3.4e38f, mx = -3.4e38f;
    for (int i = threadIdx.x; i < F4; i += 256) {
        float4 v = p[i];
        mn = fminf(mn, fminf(fminf(v.x, v.y), fminf(v.z, v.w)));
        mx = fmaxf(mx, fmaxf(fmaxf(v.x, v.y), fmaxf(v.z, v.w)));
    }
    #pragma unroll
    for (int o = 1; o < 64; o <<= 1) {
        mn = fminf(mn, __shfl_xor(mn, o));
        mx = fmaxf(mx, __shfl_xor(mx, o));
    }
    __shared__ float smn[4], smx[4];
    const int wave = threadIdx.x >> 6, lane = threadIdx.x & 63;
    if (lane == 0) { smn[wave] = mn; smx[wave] = mx; }
    __syncthreads();
    if (threadIdx.x == 0) {
        mmn[blockIdx.x] = fminf(fminf(smn[0], smn[1]), fminf(smn[2], smn[3]));
        mmx[blockIdx.x] = fmaxf(fmaxf(smx[0], smx[1]), fmaxf(smx[2], smx[3]));
    }
}

// ---------- one group of 8 bins (4 packed pairs), anchored at d = u - groupbase ----------
// P_j = (E[g+2j], E[g+2j+1]); step ratio E[k+2]/E[k] = e^{2d_k-2}:
//   H_0 = (R^2 e^-1, R^2 e^-3), H_{j+1} = H_j * e^-4, with R = e^{d-0.5}.
// R2 clamped to 1e38 so far-out points give P=0*finite=0, never 0*inf=NaN.
// E underflow (|d|>~13, FTZ) only zeroes contributions <= e^-18: negligible.
__device__ __forceinline__ void grp8(float d, v2f* __restrict__ acc) {
    float dq = d * QF;
    float E0 = __builtin_amdgcn_exp2f(-(dq * dq));
    float R  = __builtin_amdgcn_exp2f(fmaf(d, L2E, -0.5f * L2E));
    float R2 = fminf(R * R, 1e38f);
    v2f P, H;
    P.x = E0;      P.y = E0 * R;
    H.x = R2 * C1; H.y = R2 * C3;
    acc[0] += P; P *= H; H *= C4;
    acc[1] += P; P *= H; H *= C4;
    acc[2] += P; P *= H;
    acc[3] += P;
}

// ---------- pass 2: gather histogram, bins split across waves, packed pairs ----------
// Wave w owns bins 16w..16w+15 (8 v2f accumulators). Every wave traverses the
// whole chunk (shared stream -> L1 reuse). Last finished block does the KL.
__global__ __launch_bounds__(256, 6) void hist_k(const float4* __restrict__ pred,
                                                 const float4* __restrict__ tgt,
                                                 const float* __restrict__ mmn,
                                                 const float* __restrict__ mmx,
                                                 float* __restrict__ hist,
                                                 unsigned* __restrict__ done,
                                                 float* __restrict__ out) {
    const int blk   = blockIdx.x;
    const int tens  = blk & 1;
    const int batch = (blk >> 1) & (NB - 1);
    const int chunk = blk >> 5;                      // 0..CB-1
    const int wave  = threadIdx.x >> 6, lane = threadIdx.x & 63;
    const int kbase = 16 * wave;

    float vmin = mmn[batch * MMB], vmax = mmx[batch * MMB];
    #pragma unroll
    for (int i = 1; i < MMB; ++i) {
        vmin = fminf(vmin, mmn[batch * MMB + i]);
        vmax = fmaxf(vmax, mmx[batch * MMB + i]);
    }
    const float s64 = 64.0f / (vmax - vmin + EPSF);
    // d(group 0) = u - kbase = x*s64 + (b0 - kbase): fold wave's base into bias
    const float bk  = fmaf(-vmin, s64, -0.5f) - (float)kbase;

    const int F4C = NPB / 4 / CB;                    // 1024 float4 per chunk
    const float4* __restrict__ src = (tens ? tgt : pred)
        + (size_t)batch * (NPB / 4) + (size_t)chunk * F4C;

    v2f acc[8];
    #pragma unroll
    for (int i = 0; i < 8; ++i) acc[i] = (v2f)0.0f;

    #pragma unroll 1
    for (int it = 0; it < F4C / 64; ++it) {          // 16 wave-iterations
        float4 v = src[it * 64 + lane];
        float d0 = fmaf(v.x, s64, bk), d1 = fmaf(v.y, s64, bk);
        float d2 = fmaf(v.z, s64, bk), d3 = fmaf(v.w, s64, bk);
        grp8(d0, acc);          grp8(d0 - 8.0f, acc + 4);
        grp8(d1, acc);          grp8(d1 - 8.0f, acc + 4);
        grp8(d2, acc);          grp8(d2 - 8.0f, acc + 4);
        grp8(d3, acc);          grp8(d3 - 8.0f, acc + 4);
    }

    // in-wave reduce: bins disjoint across waves -> 16 butterflies, no LDS
    float a16[16];
    #pragma unroll
    for (int i = 0; i < 8; ++i) { a16[2 * i] = acc[i].x; a16[2 * i + 1] = acc[i].y; }
    float keep = 0.0f;
    #pragma unroll
    for (int i = 0; i < 16; ++i) {
        float v = a16[i];
        #pragma unroll
        for (int o = 1; o < 64; o <<= 1) v += __shfl_xor(v, o);
        if (lane == i) keep = v;
    }
    if (lane < 16)
        unsafeAtomicAdd(&hist[(tens * NB + batch) * NBINS + kbase + lane], keep);

    // ---- last block computes the KL (fp32, v_log) ----
    __shared__ bool amlast;
    __syncthreads();
    if (threadIdx.x == 0) {
        __threadfence();
        amlast = (atomicAdd(done, 1u) == (unsigned)(gridDim.x - 1));
    }
    __syncthreads();
    if (amlast) {
        __threadfence();
        __shared__ float wacc[4];
        float a = 0.0f;
        for (int b = wave; b < NB; b += 4) {
            float hp = __hip_atomic_load(&hist[b * NBINS + lane],
                                         __ATOMIC_ACQUIRE, __HIP_MEMORY_SCOPE_AGENT);
            float ht = __hip_atomic_load(&hist[(NB + b) * NBINS + lane],
                                         __ATOMIC_ACQUIRE, __HIP_MEMORY_SCOPE_AGENT);
            float sp = hp, st = ht;
            #pragma unroll
            for (int o = 1; o < 64; o <<= 1) {
                sp += __shfl_xor(sp, o);
                st += __shfl_xor(st, o);
            }
            float pp = hp / (sp + EPSF);
            float pt = ht / (st + EPSF);
            float term = pt * ((__builtin_amdgcn_logf(pt + EPSF)
                              - __builtin_amdgcn_logf(pp + EPSF)) * LN2);
            #pragma unroll
            for (int o = 1; o < 64; o <<= 1) term += __shfl_xor(term, o);
            a += term;
        }
        if (lane == 0) wacc[wave] = a;
        __syncthreads();
        if (threadIdx.x == 0)
            out[0] = 0.1f * (wacc[0] + wacc[1] + wacc[2] + wacc[3]) / (float)NB;
    }
}

extern "C" void kernel_launch(void* const* d_in, const int* in_sizes, int n_in,
                              void* d_out, int out_size, void* d_ws, size_t ws_size,
                              hipStream_t stream) {
    const float* pred = (const float*)d_in[0];
    const float* tgt  = (const float*)d_in[1];
    float*    mmn  = (float*)d_ws;
    float*    mmx  = mmn + NB * MMB;
    float*    hist = mmx + NB * MMB;
    unsigned* done = (unsigned*)(hist + 2 * NB * NBINS);
    float*    out  = (float*)d_out;

    minmax_k<<<NB * MMB, 256, 0, stream>>>((const float4*)tgt, mmn, mmx, hist, done);
    hist_k  <<<2 * NB * CB, 256, 0, stream>>>((const float4*)pred, (const float4*)tgt,
                                              mmn, mmx, hist, done, out);
}

// Round 8
// 148.190 us; speedup vs baseline: 1.0256x; 1.0256x over previous
//
#include <hip/hip_runtime.h>
#include <math.h>

// Problem constants
#define NB    16            // batches
#define NPB   (512*512)     // elements per batch
#define NBINS 64
#define MMB   16            // minmax blocks per batch
#define CB    64            // hist chunks per (tensor,batch) -> grid 2*16*64 = 2048
#define EPSF  1e-8f
#define QF    0.84932180517f   // sqrt(0.5*log2(e)); exp(-d^2/2) = exp2(-(q*d)^2)
#define L2E   1.44269504089f   // log2(e)
#define INV_E 0.36787944117f   // e^-1
#define LN2   0.69314718056f

// ws layout: mmn[256] | mmx[256] | hist[2][16][64] | done(uint)

// ---------- pass 1: per-batch block-level min/max (also zeroes hist + done) ----------
__global__ __launch_bounds__(256) void minmax_k(const float4* __restrict__ tgt,
                                                float* __restrict__ mmn,
                                                float* __restrict__ mmx,
                                                float* __restrict__ hist,
                                                unsigned* __restrict__ done) {
    const int batch = blockIdx.x >> 4, sub = blockIdx.x & 15;
    if (sub == 0 && threadIdx.x < 128) {
        const int tens = threadIdx.x >> 6, lane = threadIdx.x & 63;
        hist[(tens * NB + batch) * NBINS + lane] = 0.0f;
    }
    if (blockIdx.x == 0 && threadIdx.x == 0) *done = 0u;

    const int F4 = NPB / 4 / MMB;              // 4096 float4 per block
    const float4* p = tgt + (size_t)batch * (NPB / 4) + (size_t)sub * F4;
    float mn = 3.4e38f, mx = -3.4e38f;
    for (int i = threadIdx.x; i < F4; i += 256) {
        float4 v = p[i];
        mn = fminf(mn, fminf(fminf(v.x, v.y), fminf(v.z, v.w)));
        mx = fmaxf(mx, fmaxf(fmaxf(v.x, v.y), fmaxf(v.z, v.w)));
    }
    #pragma unroll
    for (int o = 1; o < 64; o <<= 1) {
        mn = fminf(mn, __shfl_xor(mn, o));
        mx = fmaxf(mx, __shfl_xor(mx, o));
    }
    __shared__ float smn[4], smx[4];
    const int wave = threadIdx.x >> 6, lane = threadIdx.x & 63;
    if (lane == 0) { smn[wave] = mn; smx[wave] = mx; }
    __syncthreads();
    if (threadIdx.x == 0) {
        mmn[blockIdx.x] = fminf(fminf(smn[0], smn[1]), fminf(smn[2], smn[3]));
        mmx[blockIdx.x] = fmaxf(fmaxf(smx[0], smx[1]), fmaxf(smx[2], smx[3]));
    }
}

// ---------- pass 2: gather histogram, bins split across waves ----------
// R6-proven inner loop (scalar group-of-8 recurrence): wave w owns bins
// 16w..16w+15; E(k+1)=E(k)*G, G(k+1)=G(k)/e, E re-anchored per group of 8.
// Changes vs R6: CB=64 (8 blocks/CU), launch_bounds(256,8), load prefetch.
__global__ __launch_bounds__(256, 8) void hist_k(const float4* __restrict__ pred,
                                                 const float4* __restrict__ tgt,
                                                 const float* __restrict__ mmn,
                                                 const float* __restrict__ mmx,
                                                 float* __restrict__ hist,
                                                 unsigned* __restrict__ done,
                                                 float* __restrict__ out) {
    const int blk   = blockIdx.x;
    const int tens  = blk & 1;
    const int batch = (blk >> 1) & (NB - 1);
    const int chunk = blk >> 5;                      // 0..CB-1
    const int wave  = threadIdx.x >> 6, lane = threadIdx.x & 63;
    const int kbase = 16 * wave;

    float vmin = mmn[batch * MMB], vmax = mmx[batch * MMB];
    #pragma unroll
    for (int i = 1; i < MMB; ++i) {
        vmin = fminf(vmin, mmn[batch * MMB + i]);
        vmax = fmaxf(vmax, mmx[batch * MMB + i]);
    }
    const float s64 = 64.0f / (vmax - vmin + EPSF);
    const float b0  = fmaf(-vmin, s64, -0.5f);       // u = x*s64 + b0

    const int F4C = NPB / 4 / CB;                    // 1024 float4 per chunk
    const float4* __restrict__ src = (tens ? tgt : pred)
        + (size_t)batch * (NPB / 4) + (size_t)chunk * F4C;

    float acc[16];
    #pragma unroll
    for (int k = 0; k < 16; ++k) acc[k] = 0.0f;

    const int NIT = F4C / 64;                        // 16 wave-iterations
    float4 v = src[lane];
    #pragma unroll 1
    for (int it = 0; it < NIT; ++it) {
        // prefetch next iteration's data before the compute burst
        float4 vn = src[(it < NIT - 1 ? (it + 1) * 64 : 0) + lane];
        float u0 = fmaf(v.x, s64, b0), u1 = fmaf(v.y, s64, b0);
        float u2 = fmaf(v.z, s64, b0), u3 = fmaf(v.w, s64, b0);
        float q0 = u0 * QF, q1 = u1 * QF, q2 = u2 * QF, q3 = u3 * QF;
        const float gb = -((float)kbase + 0.5f) * L2E;   // G = e^(u - kbase - 0.5)
        float G0 = __builtin_amdgcn_exp2f(fmaf(u0, L2E, gb));
        float G1 = __builtin_amdgcn_exp2f(fmaf(u1, L2E, gb));
        float G2 = __builtin_amdgcn_exp2f(fmaf(u2, L2E, gb));
        float G3 = __builtin_amdgcn_exp2f(fmaf(u3, L2E, gb));
        #pragma unroll
        for (int j = 0; j < 2; ++j) {                // 2 groups of 8 bins
            const float c = (float)(kbase + 8 * j) * QF;
            float d0 = q0 - c, d1 = q1 - c, d2 = q2 - c, d3 = q3 - c;
            float E0 = __builtin_amdgcn_exp2f(-(d0 * d0));
            float E1 = __builtin_amdgcn_exp2f(-(d1 * d1));
            float E2 = __builtin_amdgcn_exp2f(-(d2 * d2));
            float E3 = __builtin_amdgcn_exp2f(-(d3 * d3));
            #pragma unroll
            for (int i = 0; i < 8; ++i) {
                acc[8 * j + i] += (E0 + E1) + (E2 + E3);
                E0 *= G0; E1 *= G1; E2 *= G2; E3 *= G3;
                G0 *= INV_E; G1 *= INV_E; G2 *= INV_E; G3 *= INV_E;
            }
        }
        v = vn;
    }

    // in-wave reduce: bins disjoint across waves -> 16 butterflies, no LDS
    float keep = 0.0f;
    #pragma unroll
    for (int i = 0; i < 16; ++i) {
        float t = acc[i];
        #pragma unroll
        for (int o = 1; o < 64; o <<= 1) t += __shfl_xor(t, o);
        if (lane == i) keep = t;
    }
    if (lane < 16)
        unsafeAtomicAdd(&hist[(tens * NB + batch) * NBINS + kbase + lane], keep);

    // ---- last block computes the KL (fp32, v_log) ----
    __shared__ bool amlast;
    __syncthreads();
    if (threadIdx.x == 0) {
        __threadfence();
        amlast = (atomicAdd(done, 1u) == (unsigned)(gridDim.x - 1));
    }
    __syncthreads();
    if (amlast) {
        __threadfence();
        __shared__ float wacc[4];
        float a = 0.0f;
        for (int b = wave; b < NB; b += 4) {
            float hp = __hip_atomic_load(&hist[b * NBINS + lane],
                                         __ATOMIC_ACQUIRE, __HIP_MEMORY_SCOPE_AGENT);
            float ht = __hip_atomic_load(&hist[(NB + b) * NBINS + lane],
                                         __ATOMIC_ACQUIRE, __HIP_MEMORY_SCOPE_AGENT);
            float sp = hp, st = ht;
            #pragma unroll
            for (int o = 1; o < 64; o <<= 1) {
                sp += __shfl_xor(sp, o);
                st += __shfl_xor(st, o);
            }
            float pp = hp / (sp + EPSF);
            float pt = ht / (st + EPSF);
            float term = pt * ((__builtin_amdgcn_logf(pt + EPSF)
                              - __builtin_amdgcn_logf(pp + EPSF)) * LN2);
            #pragma unroll
            for (int o = 1; o < 64; o <<= 1) term += __shfl_xor(term, o);
            a += term;
        }
        if (lane == 0) wacc[wave] = a;
        __syncthreads();
        if (threadIdx.x == 0)
            out[0] = 0.1f * (wacc[0] + wacc[1] + wacc[2] + wacc[3]) / (float)NB;
    }
}

extern "C" void kernel_launch(void* const* d_in, const int* in_sizes, int n_in,
                              void* d_out, int out_size, void* d_ws, size_t ws_size,
                              hipStream_t stream) {
    const float* pred = (const float*)d_in[0];
    const float* tgt  = (const float*)d_in[1];
    float*    mmn  = (float*)d_ws;
    float*    mmx  = mmn + NB * MMB;
    float*    hist = mmx + NB * MMB;
    unsigned* done = (unsigned*)(hist + 2 * NB * NBINS);
    float*    out  = (float*)d_out;

    minmax_k<<<NB * MMB, 256, 0, stream>>>((const float4*)tgt, mmn, mmx, hist, done);
    hist_k  <<<2 * NB * CB, 256, 0, stream>>>((const float4*)pred, (const float4*)tgt,
                                              mmn, mmx, hist, done, out);
}

// Round 9
// 140.942 us; speedup vs baseline: 1.0784x; 1.0514x over previous
//
#include <hip/hip_runtime.h>
#include <math.h>

// Problem constants
#define NB    16            // batches
#define NPB   (512*512)     // elements per batch
#define NBINS 64
#define MMB   16            // minmax blocks per batch
#define CB    32            // hist chunks per (tensor,batch) -> grid 2*16*32 = 1024
#define EPSF  1e-8f
#define QF    0.84932180517f   // sqrt(0.5*log2(e)); exp(-d^2/2) = exp2(-(q*d)^2)
#define L2E   1.44269504089f   // log2(e)
#define INV_E 0.36787944117f   // e^-1
#define LN2   0.69314718056f

// ws layout: mmn[256] | mmx[256] | hist[2][16][64] | done(uint)

// ---------- pass 1: per-batch block-level min/max (also zeroes hist + done) ----------
__global__ __launch_bounds__(256) void minmax_k(const float4* __restrict__ tgt,
                                                float* __restrict__ mmn,
                                                float* __restrict__ mmx,
                                                float* __restrict__ hist,
                                                unsigned* __restrict__ done) {
    const int batch = blockIdx.x >> 4, sub = blockIdx.x & 15;
    if (sub == 0 && threadIdx.x < 128) {
        const int tens = threadIdx.x >> 6, lane = threadIdx.x & 63;
        hist[(tens * NB + batch) * NBINS + lane] = 0.0f;
    }
    if (blockIdx.x == 0 && threadIdx.x == 0) *done = 0u;

    const int F4 = NPB / 4 / MMB;              // 4096 float4 per block
    const float4* p = tgt + (size_t)batch * (NPB / 4) + (size_t)sub * F4;
    float mn = 3.4e38f, mx = -3.4e38f;
    for (int i = threadIdx.x; i < F4; i += 256) {
        float4 v = p[i];
        mn = fminf(mn, fminf(fminf(v.x, v.y), fminf(v.z, v.w)));
        mx = fmaxf(mx, fmaxf(fmaxf(v.x, v.y), fmaxf(v.z, v.w)));
    }
    #pragma unroll
    for (int o = 1; o < 64; o <<= 1) {
        mn = fminf(mn, __shfl_xor(mn, o));
        mx = fmaxf(mx, __shfl_xor(mx, o));
    }
    __shared__ float smn[4], smx[4];
    const int wave = threadIdx.x >> 6, lane = threadIdx.x & 63;
    if (lane == 0) { smn[wave] = mn; smx[wave] = mx; }
    __syncthreads();
    if (threadIdx.x == 0) {
        mmn[blockIdx.x] = fminf(fminf(smn[0], smn[1]), fminf(smn[2], smn[3]));
        mmx[blockIdx.x] = fmaxf(fmaxf(smx[0], smx[1]), fmaxf(smx[2], smx[3]));
    }
}

// ---------- pass 2: gather histogram, bins split across waves ----------
// R6 config (CB=32, lb(256,6)) + 1-deep load prefetch — the ONLY change vs R6.
// Wave w owns bins 16w..16w+15; group-of-8 recurrence E(k+1)=E(k)*G,
// G(k+1)=G(k)/e, E re-anchored per group of 8 (underflow-safe, G finite).
__global__ __launch_bounds__(256, 6) void hist_k(const float4* __restrict__ pred,
                                                 const float4* __restrict__ tgt,
                                                 const float* __restrict__ mmn,
                                                 const float* __restrict__ mmx,
                                                 float* __restrict__ hist,
                                                 unsigned* __restrict__ done,
                                                 float* __restrict__ out) {
    const int blk   = blockIdx.x;
    const int tens  = blk & 1;
    const int batch = (blk >> 1) & (NB - 1);
    const int chunk = blk >> 5;                      // 0..CB-1
    const int wave  = threadIdx.x >> 6, lane = threadIdx.x & 63;
    const int kbase = 16 * wave;

    const int F4C = NPB / 4 / CB;                    // 2048 float4 per chunk
    const float4* __restrict__ src = (tens ? tgt : pred)
        + (size_t)batch * (NPB / 4) + (size_t)chunk * F4C;

    // issue first data load before the prologue reduction (overlap)
    float4 v = src[lane];

    float vmin = mmn[batch * MMB], vmax = mmx[batch * MMB];
    #pragma unroll
    for (int i = 1; i < MMB; ++i) {
        vmin = fminf(vmin, mmn[batch * MMB + i]);
        vmax = fmaxf(vmax, mmx[batch * MMB + i]);
    }
    const float s64 = 64.0f / (vmax - vmin + EPSF);
    const float b0  = fmaf(-vmin, s64, -0.5f);       // u = x*s64 + b0
    const float gb  = -((float)kbase + 0.5f) * L2E;  // G = e^(u - kbase - 0.5)

    float acc[16];
    #pragma unroll
    for (int k = 0; k < 16; ++k) acc[k] = 0.0f;

    const int NIT = F4C / 64;                        // 32 wave-iterations
    #pragma unroll 1
    for (int it = 0; it < NIT; ++it) {
        // prefetch next iteration's data; its latency hides under the burst
        float4 vn = src[(it < NIT - 1 ? (it + 1) * 64 : 0) + lane];
        float u0 = fmaf(v.x, s64, b0), u1 = fmaf(v.y, s64, b0);
        float u2 = fmaf(v.z, s64, b0), u3 = fmaf(v.w, s64, b0);
        float q0 = u0 * QF, q1 = u1 * QF, q2 = u2 * QF, q3 = u3 * QF;
        float G0 = __builtin_amdgcn_exp2f(fmaf(u0, L2E, gb));
        float G1 = __builtin_amdgcn_exp2f(fmaf(u1, L2E, gb));
        float G2 = __builtin_amdgcn_exp2f(fmaf(u2, L2E, gb));
        float G3 = __builtin_amdgcn_exp2f(fmaf(u3, L2E, gb));
        #pragma unroll
        for (int j = 0; j < 2; ++j) {                // 2 groups of 8 bins
            const float c = (float)(kbase + 8 * j) * QF;
            float d0 = q0 - c, d1 = q1 - c, d2 = q2 - c, d3 = q3 - c;
            float E0 = __builtin_amdgcn_exp2f(-(d0 * d0));
            float E1 = __builtin_amdgcn_exp2f(-(d1 * d1));
            float E2 = __builtin_amdgcn_exp2f(-(d2 * d2));
            float E3 = __builtin_amdgcn_exp2f(-(d3 * d3));
            #pragma unroll
            for (int i = 0; i < 8; ++i) {
                acc[8 * j + i] += (E0 + E1) + (E2 + E3);
                E0 *= G0; E1 *= G1; E2 *= G2; E3 *= G3;
                G0 *= INV_E; G1 *= INV_E; G2 *= INV_E; G3 *= INV_E;
            }
        }
        v = vn;
    }

    // in-wave reduce: bins disjoint across waves -> 16 butterflies, no LDS
    float keep = 0.0f;
    #pragma unroll
    for (int i = 0; i < 16; ++i) {
        float t = acc[i];
        #pragma unroll
        for (int o = 1; o < 64; o <<= 1) t += __shfl_xor(t, o);
        if (lane == i) keep = t;
    }
    if (lane < 16)
        unsafeAtomicAdd(&hist[(tens * NB + batch) * NBINS + kbase + lane], keep);

    // ---- last block computes the KL (fp32, v_log) ----
    __shared__ bool amlast;
    __syncthreads();
    if (threadIdx.x == 0) {
        __threadfence();
        amlast = (atomicAdd(done, 1u) == (unsigned)(gridDim.x - 1));
    }
    __syncthreads();
    if (amlast) {
        __threadfence();
        __shared__ float wacc[4];
        float a = 0.0f;
        for (int b = wave; b < NB; b += 4) {
            float hp = __hip_atomic_load(&hist[b * NBINS + lane],
                                         __ATOMIC_ACQUIRE, __HIP_MEMORY_SCOPE_AGENT);
            float ht = __hip_atomic_load(&hist[(NB + b) * NBINS + lane],
                                         __ATOMIC_ACQUIRE, __HIP_MEMORY_SCOPE_AGENT);
            float sp = hp, st = ht;
            #pragma unroll
            for (int o = 1; o < 64; o <<= 1) {
                sp += __shfl_xor(sp, o);
                st += __shfl_xor(st, o);
            }
            float pp = hp / (sp + EPSF);
            float pt = ht / (st + EPSF);
            float term = pt * ((__builtin_amdgcn_logf(pt + EPSF)
                              - __builtin_amdgcn_logf(pp + EPSF)) * LN2);
            #pragma unroll
            for (int o = 1; o < 64; o <<= 1) term += __shfl_xor(term, o);
            a += term;
        }
        if (lane == 0) wacc[wave] = a;
        __syncthreads();
        if (threadIdx.x == 0)
            out[0] = 0.1f * (wacc[0] + wacc[1] + wacc[2] + wacc[3]) / (float)NB;
    }
}

extern "C" void kernel_launch(void* const* d_in, const int* in_sizes, int n_in,
                              void* d_out, int out_size, void* d_ws, size_t ws_size,
                              hipStream_t stream) {
    const float* pred = (const float*)d_in[0];
    const float* tgt  = (const float*)d_in[1];
    float*    mmn  = (float*)d_ws;
    float*    mmx  = mmn + NB * MMB;
    float*    hist = mmx + NB * MMB;
    unsigned* done = (unsigned*)(hist + 2 * NB * NBINS);
    float*    out  = (float*)d_out;

    minmax_k<<<NB * MMB, 256, 0, stream>>>((const float4*)tgt, mmn, mmx, hist, done);
    hist_k  <<<2 * NB * CB, 256, 0, stream>>>((const float4*)pred, (const float4*)tgt,
                                              mmn, mmx, hist, done, out);
}

// Round 10
// 122.151 us; speedup vs baseline: 1.2442x; 1.1538x over previous
//
#include <hip/hip_runtime.h>
#include <math.h>

// Problem constants
#define NB    16            // batches
#define NPB   (512*512)     // elements per batch
#define NBINS 64
#define MMB   16            // minmax blocks per batch
#define CB    64            // hist chunks per (tensor,batch) -> grid 2*16*64 = 2048
#define EPSF  1e-8f
#define QF    0.84932180517f   // sqrt(0.5*log2(e)); exp(-d^2/2) = exp2(-(q*d)^2)
#define L2E   1.44269504089f   // log2(e)
#define INV_E 0.36787944117f   // e^-1
#define LN2   0.69314718056f

// ws layout: mmn[256] | mmx[256] | hist[2][16][64]

// ---------- pass 1: per-batch block-level min/max (also zeroes hist) ----------
__global__ __launch_bounds__(256) void minmax_k(const float4* __restrict__ tgt,
                                                float* __restrict__ mmn,
                                                float* __restrict__ mmx,
                                                float* __restrict__ hist) {
    const int batch = blockIdx.x >> 4, sub = blockIdx.x & 15;
    if (sub == 0 && threadIdx.x < 128) {
        const int tens = threadIdx.x >> 6, lane = threadIdx.x & 63;
        hist[(tens * NB + batch) * NBINS + lane] = 0.0f;
    }

    const int F4 = NPB / 4 / MMB;              // 4096 float4 per block
    const float4* p = tgt + (size_t)batch * (NPB / 4) + (size_t)sub * F4;
    float mn = 3.4e38f, mx = -3.4e38f;
    for (int i = threadIdx.x; i < F4; i += 256) {
        float4 v = p[i];
        mn = fminf(mn, fminf(fminf(v.x, v.y), fminf(v.z, v.w)));
        mx = fmaxf(mx, fmaxf(fmaxf(v.x, v.y), fmaxf(v.z, v.w)));
    }
    #pragma unroll
    for (int o = 1; o < 64; o <<= 1) {
        mn = fminf(mn, __shfl_xor(mn, o));
        mx = fmaxf(mx, __shfl_xor(mx, o));
    }
    __shared__ float smn[4], smx[4];
    const int wave = threadIdx.x >> 6, lane = threadIdx.x & 63;
    if (lane == 0) { smn[wave] = mn; smx[wave] = mx; }
    __syncthreads();
    if (threadIdx.x == 0) {
        mmn[blockIdx.x] = fminf(fminf(smn[0], smn[1]), fminf(smn[2], smn[3]));
        mmx[blockIdx.x] = fmaxf(fmaxf(smx[0], smx[1]), fmaxf(smx[2], smx[3]));
    }
}

// ---------- pass 2: gather histogram, bins split across waves ----------
// Scalar group-of-8 recurrence (R6-proven): wave w owns bins 16w..16w+15;
// E(k+1)=E(k)*G, G(k+1)=G(k)/e, E re-anchored by fresh exp2 per group of 8
// (underflow-safe). 1-deep load prefetch (R9-proven). NO fence / NO fused
// finalize: the per-block __threadfence + single-cacheline done-atomic was
// a serialized ~60cyc/block tail that scaled with grid size (R8 paradox).
__global__ __launch_bounds__(256, 8) void hist_k(const float4* __restrict__ pred,
                                                 const float4* __restrict__ tgt,
                                                 const float* __restrict__ mmn,
                                                 const float* __restrict__ mmx,
                                                 float* __restrict__ hist) {
    const int blk   = blockIdx.x;
    const int tens  = blk & 1;
    const int batch = (blk >> 1) & (NB - 1);
    const int chunk = blk >> 5;                      // 0..CB-1
    const int wave  = threadIdx.x >> 6, lane = threadIdx.x & 63;
    const int kbase = 16 * wave;

    const int F4C = NPB / 4 / CB;                    // 1024 float4 per chunk
    const float4* __restrict__ src = (tens ? tgt : pred)
        + (size_t)batch * (NPB / 4) + (size_t)chunk * F4C;

    // issue first data load before the prologue reduction (overlap)
    float4 v = src[lane];

    float vmin = mmn[batch * MMB], vmax = mmx[batch * MMB];
    #pragma unroll
    for (int i = 1; i < MMB; ++i) {
        vmin = fminf(vmin, mmn[batch * MMB + i]);
        vmax = fmaxf(vmax, mmx[batch * MMB + i]);
    }
    const float s64 = 64.0f / (vmax - vmin + EPSF);
    const float b0  = fmaf(-vmin, s64, -0.5f);       // u = x*s64 + b0
    const float gb  = -((float)kbase + 0.5f) * L2E;  // G = e^(u - kbase - 0.5)

    float acc[16];
    #pragma unroll
    for (int k = 0; k < 16; ++k) acc[k] = 0.0f;

    const int NIT = F4C / 64;                        // 16 wave-iterations
    #pragma unroll 1
    for (int it = 0; it < NIT; ++it) {
        // prefetch next iteration's data; latency hides under the burst
        float4 vn = src[(it < NIT - 1 ? (it + 1) * 64 : 0) + lane];
        float u0 = fmaf(v.x, s64, b0), u1 = fmaf(v.y, s64, b0);
        float u2 = fmaf(v.z, s64, b0), u3 = fmaf(v.w, s64, b0);
        float q0 = u0 * QF, q1 = u1 * QF, q2 = u2 * QF, q3 = u3 * QF;
        float G0 = __builtin_amdgcn_exp2f(fmaf(u0, L2E, gb));
        float G1 = __builtin_amdgcn_exp2f(fmaf(u1, L2E, gb));
        float G2 = __builtin_amdgcn_exp2f(fmaf(u2, L2E, gb));
        float G3 = __builtin_amdgcn_exp2f(fmaf(u3, L2E, gb));
        #pragma unroll
        for (int j = 0; j < 2; ++j) {                // 2 groups of 8 bins
            const float c = (float)(kbase + 8 * j) * QF;
            float d0 = q0 - c, d1 = q1 - c, d2 = q2 - c, d3 = q3 - c;
            float E0 = __builtin_amdgcn_exp2f(-(d0 * d0));
            float E1 = __builtin_amdgcn_exp2f(-(d1 * d1));
            float E2 = __builtin_amdgcn_exp2f(-(d2 * d2));
            float E3 = __builtin_amdgcn_exp2f(-(d3 * d3));
            #pragma unroll
            for (int i = 0; i < 8; ++i) {
                acc[8 * j + i] += (E0 + E1) + (E2 + E3);
                E0 *= G0; E1 *= G1; E2 *= G2; E3 *= G3;
                G0 *= INV_E; G1 *= INV_E; G2 *= INV_E; G3 *= INV_E;
            }
        }
        v = vn;
    }

    // in-wave reduce: bins disjoint across waves -> 16 butterflies, no LDS
    float keep = 0.0f;
    #pragma unroll
    for (int i = 0; i < 16; ++i) {
        float t = acc[i];
        #pragma unroll
        for (int o = 1; o < 64; o <<= 1) t += __shfl_xor(t, o);
        if (lane == i) keep = t;
    }
    if (lane < 16)
        unsafeAtomicAdd(&hist[(tens * NB + batch) * NBINS + kbase + lane], keep);
}

// ---------- pass 3: KL (fp32, v_log), tiny ----------
__global__ __launch_bounds__(256) void final_k(const float* __restrict__ hist,
                                               float* __restrict__ out) {
    const int lane = threadIdx.x & 63, wave = threadIdx.x >> 6;
    __shared__ float wacc[4];
    float a = 0.0f;
    for (int b = wave; b < NB; b += 4) {
        float hp = hist[b * NBINS + lane];
        float ht = hist[(NB + b) * NBINS + lane];
        float sp = hp, st = ht;
        #pragma unroll
        for (int o = 1; o < 64; o <<= 1) {
            sp += __shfl_xor(sp, o);
            st += __shfl_xor(st, o);
        }
        float pp = hp / (sp + EPSF);
        float pt = ht / (st + EPSF);
        float term = pt * ((__builtin_amdgcn_logf(pt + EPSF)
                          - __builtin_amdgcn_logf(pp + EPSF)) * LN2);
        #pragma unroll
        for (int o = 1; o < 64; o <<= 1) term += __shfl_xor(term, o);
        a += term;
    }
    if (lane == 0) wacc[wave] = a;
    __syncthreads();
    if (threadIdx.x == 0)
        out[0] = 0.1f * (wacc[0] + wacc[1] + wacc[2] + wacc[3]) / (float)NB;
}

extern "C" void kernel_launch(void* const* d_in, const int* in_sizes, int n_in,
                              void* d_out, int out_size, void* d_ws, size_t ws_size,
                              hipStream_t stream) {
    const float* pred = (const float*)d_in[0];
    const float* tgt  = (const float*)d_in[1];
    float* mmn  = (float*)d_ws;
    float* mmx  = mmn + NB * MMB;
    float* hist = mmx + NB * MMB;
    float* out  = (float*)d_out;

    minmax_k<<<NB * MMB, 256, 0, stream>>>((const float4*)tgt, mmn, mmx, hist);
    hist_k  <<<2 * NB * CB, 256, 0, stream>>>((const float4*)pred, (const float4*)tgt,
                                              mmn, mmx, hist);
    final_k <<<1, 256, 0, stream>>>(hist, out);
}

// Round 11
// 118.629 us; speedup vs baseline: 1.2812x; 1.0297x over previous
//
#include <hip/hip_runtime.h>
#include <math.h>

// Problem constants
#define NB    16            // batches
#define NPB   (512*512)     // elements per batch
#define NBINS 64
#define MMB   16            // minmax blocks per batch
#define CB    64            // hist chunks per (tensor,batch) -> grid 2*16*64 = 2048
#define EPSF  1e-8f
#define QF    0.84932180517f   // sqrt(0.5*log2(e)); exp(-d^2/2) = exp2(-(q*d)^2)
#define L2E   1.44269504089f   // log2(e)
#define LN2   0.69314718056f
#define C8G   3.35462627903e-4f  // e^-8 (group-1 growth-rate adjust)

// ws layout: mmn[256] | mmx[256] | hist[2][16][64]

// ---------- pass 1: per-batch block-level min/max (also zeroes hist) ----------
__global__ __launch_bounds__(256) void minmax_k(const float4* __restrict__ tgt,
                                                float* __restrict__ mmn,
                                                float* __restrict__ mmx,
                                                float* __restrict__ hist) {
    const int batch = blockIdx.x >> 4, sub = blockIdx.x & 15;
    if (sub == 0 && threadIdx.x < 128) {
        const int tens = threadIdx.x >> 6, lane = threadIdx.x & 63;
        hist[(tens * NB + batch) * NBINS + lane] = 0.0f;
    }

    const int F4 = NPB / 4 / MMB;              // 4096 float4 per block
    const float4* p = tgt + (size_t)batch * (NPB / 4) + (size_t)sub * F4;
    float mn = 3.4e38f, mx = -3.4e38f;
    for (int i = threadIdx.x; i < F4; i += 256) {
        float4 v = p[i];
        mn = fminf(mn, fminf(fminf(v.x, v.y), fminf(v.z, v.w)));
        mx = fmaxf(mx, fmaxf(fmaxf(v.x, v.y), fmaxf(v.z, v.w)));
    }
    #pragma unroll
    for (int o = 1; o < 64; o <<= 1) {
        mn = fminf(mn, __shfl_xor(mn, o));
        mx = fmaxf(mx, __shfl_xor(mx, o));
    }
    __shared__ float smn[4], smx[4];
    const int wave = threadIdx.x >> 6, lane = threadIdx.x & 63;
    if (lane == 0) { smn[wave] = mn; smx[wave] = mx; }
    __syncthreads();
    if (threadIdx.x == 0) {
        mmn[blockIdx.x] = fminf(fminf(smn[0], smn[1]), fminf(smn[2], smn[3]));
        mmx[blockIdx.x] = fmaxf(fmaxf(smx[0], smx[1]), fmaxf(smx[2], smx[3]));
    }
}

// ---------- pass 2: gather histogram, bins split across waves ----------
// Wave w owns bins 16w..16w+15, two groups of 8. Within a group anchored at
// base m: E(m+j) = A * r^j * C_j, where A = exp(-d0^2/2) (fresh exp2 per
// group, underflow-safe), r = e^{d0} (loop-invariant per point per group),
// C_j = e^{-j^2/2} compile-time constants folded into the accumulate FMA:
//   acc[j] = fma(T, C_j, acc[j]); T *= r;     // 2 ops/point-bin (was 3)
// A>0 requires |d0|<13.2 where r<5.4e5 (no overflow); r clamped to 1e30 so
// the A==0 far-point case cannot form 0*inf=NaN. 1-deep load prefetch.
__global__ __launch_bounds__(256, 8) void hist_k(const float4* __restrict__ pred,
                                                 const float4* __restrict__ tgt,
                                                 const float* __restrict__ mmn,
                                                 const float* __restrict__ mmx,
                                                 float* __restrict__ hist) {
    const int blk   = blockIdx.x;
    const int tens  = blk & 1;
    const int batch = (blk >> 1) & (NB - 1);
    const int chunk = blk >> 5;                      // 0..CB-1
    const int wave  = threadIdx.x >> 6, lane = threadIdx.x & 63;
    const int kbase = 16 * wave;

    const int F4C = NPB / 4 / CB;                    // 1024 float4 per chunk
    const float4* __restrict__ src = (tens ? tgt : pred)
        + (size_t)batch * (NPB / 4) + (size_t)chunk * F4C;

    // issue first data load before the prologue reduction (overlap)
    float4 v = src[lane];

    float vmin = mmn[batch * MMB], vmax = mmx[batch * MMB];
    #pragma unroll
    for (int i = 1; i < MMB; ++i) {
        vmin = fminf(vmin, mmn[batch * MMB + i]);
        vmax = fmaxf(vmax, mmx[batch * MMB + i]);
    }
    const float s64 = 64.0f / (vmax - vmin + EPSF);
    const float bk  = fmaf(-vmin, s64, -0.5f) - (float)kbase;  // d = x*s64 + bk

    float acc[16];
    #pragma unroll
    for (int k = 0; k < 16; ++k) acc[k] = 0.0f;

    // e^{-j^2/2}, j = 0..7
    const float Cj[8] = { 1.0f, 0.60653065971f, 0.13533528324f, 0.01110899654f,
                          3.35462627903e-4f, 3.72665317208e-6f,
                          1.52299797447e-8f, 2.28973484833e-11f };

    const int NIT = F4C / 64;                        // 16 wave-iterations
    #pragma unroll 1
    for (int it = 0; it < NIT; ++it) {
        // prefetch next iteration's data; latency hides under the burst
        float4 vn = src[(it < NIT - 1 ? (it + 1) * 64 : 0) + lane];
        float d0 = fmaf(v.x, s64, bk), d1 = fmaf(v.y, s64, bk);
        float d2 = fmaf(v.z, s64, bk), d3 = fmaf(v.w, s64, bk);
        // r = e^d, clamped finite (only matters when anchor A == 0)
        float r0 = fminf(__builtin_amdgcn_exp2f(d0 * L2E), 1e30f);
        float r1 = fminf(__builtin_amdgcn_exp2f(d1 * L2E), 1e30f);
        float r2 = fminf(__builtin_amdgcn_exp2f(d2 * L2E), 1e30f);
        float r3 = fminf(__builtin_amdgcn_exp2f(d3 * L2E), 1e30f);
        // ---- group 0 (bins kbase..kbase+7), anchor at d ----
        {
            float t0 = d0 * QF, t1 = d1 * QF, t2 = d2 * QF, t3 = d3 * QF;
            float T0 = __builtin_amdgcn_exp2f(-(t0 * t0));
            float T1 = __builtin_amdgcn_exp2f(-(t1 * t1));
            float T2 = __builtin_amdgcn_exp2f(-(t2 * t2));
            float T3 = __builtin_amdgcn_exp2f(-(t3 * t3));
            #pragma unroll
            for (int j = 0; j < 8; ++j) {
                acc[j] = fmaf(T0, Cj[j], acc[j]);
                acc[j] = fmaf(T1, Cj[j], acc[j]);
                acc[j] = fmaf(T2, Cj[j], acc[j]);
                acc[j] = fmaf(T3, Cj[j], acc[j]);
                T0 *= r0; T1 *= r1; T2 *= r2; T3 *= r3;
            }
        }
        // ---- group 1 (bins kbase+8..kbase+15), anchor at d-8, rate r*e^-8 ----
        {
            float e0 = d0 - 8.0f, e1 = d1 - 8.0f, e2 = d2 - 8.0f, e3 = d3 - 8.0f;
            float s0 = e0 * QF, s1 = e1 * QF, s2 = e2 * QF, s3 = e3 * QF;
            float U0 = __builtin_amdgcn_exp2f(-(s0 * s0));
            float U1 = __builtin_amdgcn_exp2f(-(s1 * s1));
            float U2 = __builtin_amdgcn_exp2f(-(s2 * s2));
            float U3 = __builtin_amdgcn_exp2f(-(s3 * s3));
            float g0 = r0 * C8G, g1 = r1 * C8G, g2 = r2 * C8G, g3 = r3 * C8G;
            #pragma unroll
            for (int j = 0; j < 8; ++j) {
                acc[8 + j] = fmaf(U0, Cj[j], acc[8 + j]);
                acc[8 + j] = fmaf(U1, Cj[j], acc[8 + j]);
                acc[8 + j] = fmaf(U2, Cj[j], acc[8 + j]);
                acc[8 + j] = fmaf(U3, Cj[j], acc[8 + j]);
                U0 *= g0; U1 *= g1; U2 *= g2; U3 *= g3;
            }
        }
        v = vn;
    }

    // in-wave reduce: bins disjoint across waves -> 16 butterflies, no LDS
    float keep = 0.0f;
    #pragma unroll
    for (int i = 0; i < 16; ++i) {
        float t = acc[i];
        #pragma unroll
        for (int o = 1; o < 64; o <<= 1) t += __shfl_xor(t, o);
        if (lane == i) keep = t;
    }
    if (lane < 16)
        unsafeAtomicAdd(&hist[(tens * NB + batch) * NBINS + kbase + lane], keep);
}

// ---------- pass 3: KL (fp32, v_log), tiny ----------
__global__ __launch_bounds__(256) void final_k(const float* __restrict__ hist,
                                               float* __restrict__ out) {
    const int lane = threadIdx.x & 63, wave = threadIdx.x >> 6;
    __shared__ float wacc[4];
    float a = 0.0f;
    for (int b = wave; b < NB; b += 4) {
        float hp = hist[b * NBINS + lane];
        float ht = hist[(NB + b) * NBINS + lane];
        float sp = hp, st = ht;
        #pragma unroll
        for (int o = 1; o < 64; o <<= 1) {
            sp += __shfl_xor(sp, o);
            st += __shfl_xor(st, o);
        }
        float pp = hp / (sp + EPSF);
        float pt = ht / (st + EPSF);
        float term = pt * ((__builtin_amdgcn_logf(pt + EPSF)
                          - __builtin_amdgcn_logf(pp + EPSF)) * LN2);
        #pragma unroll
        for (int o = 1; o < 64; o <<= 1) term += __shfl_xor(term, o);
        a += term;
    }
    if (lane == 0) wacc[wave] = a;
    __syncthreads();
    if (threadIdx.x == 0)
        out[0] = 0.1f * (wacc[0] + wacc[1] + wacc[2] + wacc[3]) / (float)NB;
}

extern "C" void kernel_launch(void* const* d_in, const int* in_sizes, int n_in,
                              void* d_out, int out_size, void* d_ws, size_t ws_size,
                              hipStream_t stream) {
    const float* pred = (const float*)d_in[0];
    const float* tgt  = (const float*)d_in[1];
    float* mmn  = (float*)d_ws;
    float* mmx  = mmn + NB * MMB;
    float* hist = mmx + NB * MMB;
    float* out  = (float*)d_out;

    minmax_k<<<NB * MMB, 256, 0, stream>>>((const float4*)tgt, mmn, mmx, hist);
    hist_k  <<<2 * NB * CB, 256, 0, stream>>>((const float4*)pred, (const float4*)tgt,
                                              mmn, mmx, hist);
    final_k <<<1, 256, 0, stream>>>(hist, out);
}

// Round 12
// 115.429 us; speedup vs baseline: 1.3167x; 1.0277x over previous
//
#include <hip/hip_runtime.h>
#include <math.h>

// Problem constants
#define NB    16            // batches
#define NPB   (512*512)     // elements per batch
#define NBINS 64
#define MMB   64            // minmax blocks per batch (grid 1024 = 4/CU)
#define CB    64            // hist chunks per (tensor,batch) -> grid 2*16*64 = 2048
#define EPSF  1e-8f
#define QF    0.84932180517f   // sqrt(0.5*log2(e)); exp(-d^2/2) = exp2(-(q*d)^2)
#define L2E   1.44269504089f   // log2(e)
#define LN2   0.69314718056f
#define RCLMP 1e30f

// ws layout: mmn[1024] | mmx[1024] | hist[2][16][64]

// ---------- pass 1: per-batch block-level min/max (also zeroes hist) ----------
__global__ __launch_bounds__(256) void minmax_k(const float4* __restrict__ tgt,
                                                float* __restrict__ mmn,
                                                float* __restrict__ mmx,
                                                float* __restrict__ hist) {
    const int batch = blockIdx.x / MMB, sub = blockIdx.x % MMB;
    if (sub == 0 && threadIdx.x < 128) {
        const int tens = threadIdx.x >> 6, lane = threadIdx.x & 63;
        hist[(tens * NB + batch) * NBINS + lane] = 0.0f;
    }

    const int F4 = NPB / 4 / MMB;              // 1024 float4 per block
    const float4* p = tgt + (size_t)batch * (NPB / 4) + (size_t)sub * F4;
    float mn = 3.4e38f, mx = -3.4e38f;
    #pragma unroll
    for (int i = 0; i < F4 / 256; ++i) {       // 4 iterations
        float4 v = p[i * 256 + threadIdx.x];
        mn = fminf(mn, fminf(fminf(v.x, v.y), fminf(v.z, v.w)));
        mx = fmaxf(mx, fmaxf(fmaxf(v.x, v.y), fmaxf(v.z, v.w)));
    }
    #pragma unroll
    for (int o = 1; o < 64; o <<= 1) {
        mn = fminf(mn, __shfl_xor(mn, o));
        mx = fmaxf(mx, __shfl_xor(mx, o));
    }
    __shared__ float smn[4], smx[4];
    const int wave = threadIdx.x >> 6, lane = threadIdx.x & 63;
    if (lane == 0) { smn[wave] = mn; smx[wave] = mx; }
    __syncthreads();
    if (threadIdx.x == 0) {
        mmn[blockIdx.x] = fminf(fminf(smn[0], smn[1]), fminf(smn[2], smn[3]));
        mmx[blockIdx.x] = fmaxf(fmaxf(smx[0], smx[1]), fmaxf(smx[2], smx[3]));
    }
}

// ---------- pass 2: gather histogram, bins split across waves ----------
// Wave w owns bins 16w..16w+15, ONE anchor at the group middle (kbase+8):
//   d8 = u - (kbase+8);  A = exp(-d8^2/2);  r = e^{d8}, ri = e^{-d8}
//   E(mid+i) = A * r^i * C_i,  E(mid-i) = A * ri^i * C_i,  C_i = e^{-i^2/2}
// C_i are compile-time constants folded into the accumulate FMA (2 ops/bin).
// ri comes from exp2 with a free neg-modifier on x = d8*L2E.  Anchor live
// range |d8|<13.2 covers every bin within 8 of the anchor (worst case needs
// A=e^-32, far above denormal); outside it A==0 and clamped r/ri keep the
// chain at exact 0 (0*1e30 finite). 1-deep load prefetch (R9).
// No fence / fused finalize: per-block __threadfence + one-cacheline atomic
// serialized ~60cyc/block and scaled with grid (R8 paradox, fixed R10).
__global__ __launch_bounds__(256, 8) void hist_k(const float4* __restrict__ pred,
                                                 const float4* __restrict__ tgt,
                                                 const float* __restrict__ mmn,
                                                 const float* __restrict__ mmx,
                                                 float* __restrict__ hist) {
    const int blk   = blockIdx.x;
    const int tens  = blk & 1;
    const int batch = (blk >> 1) & (NB - 1);
    const int chunk = blk >> 5;                      // 0..CB-1
    const int wave  = threadIdx.x >> 6, lane = threadIdx.x & 63;
    const int kbase = 16 * wave;

    const int F4C = NPB / 4 / CB;                    // 1024 float4 per chunk
    const float4* __restrict__ src = (tens ? tgt : pred)
        + (size_t)batch * (NPB / 4) + (size_t)chunk * F4C;

    // issue first data load before the prologue reduction (overlap)
    float4 v = src[lane];

    // lane-parallel reduce of this batch's 64 minmax partials
    float vmin = mmn[batch * MMB + lane];
    float vmax = mmx[batch * MMB + lane];
    #pragma unroll
    for (int o = 1; o < 64; o <<= 1) {
        vmin = fminf(vmin, __shfl_xor(vmin, o));
        vmax = fmaxf(vmax, __shfl_xor(vmax, o));
    }
    const float s64 = 64.0f / (vmax - vmin + EPSF);
    // d8 = u - (kbase+8) = x*s64 + bk8
    const float bk8 = fmaf(-vmin, s64, -0.5f) - (float)(kbase + 8);

    float acc[16];
    #pragma unroll
    for (int k = 0; k < 16; ++k) acc[k] = 0.0f;

    // C_i = e^{-i^2/2}, i = 0..8
    const float C1 = 0.60653065971f,   C2 = 0.13533528324f,
                C3 = 0.01110899654f,   C4 = 3.35462627903e-4f,
                C5 = 3.72665317208e-6f, C6 = 1.52299797447e-8f,
                C7 = 2.28973484833e-11f, C8 = 1.26641655490e-14f;

    const int NIT = F4C / 64;                        // 16 wave-iterations
    #pragma unroll 1
    for (int it = 0; it < NIT; ++it) {
        // prefetch next iteration's data; latency hides under the burst
        float4 vn = src[(it < NIT - 1 ? (it + 1) * 64 : 0) + lane];
        #pragma unroll
        for (int pq = 0; pq < 4; ++pq) {
            float xin = (pq == 0) ? v.x : (pq == 1) ? v.y : (pq == 2) ? v.z : v.w;
            float d  = fmaf(xin, s64, bk8);
            float x  = d * L2E;
            float r  = fminf(__builtin_amdgcn_exp2f(x),  RCLMP);
            float ri = fminf(__builtin_amdgcn_exp2f(-x), RCLMP);
            float t  = d * QF;
            float A  = __builtin_amdgcn_exp2f(-(t * t));
            // up: bins 8..15
            float T = A;
            acc[8] += A;
            T *= r;  acc[9]  = fmaf(T, C1, acc[9]);
            T *= r;  acc[10] = fmaf(T, C2, acc[10]);
            T *= r;  acc[11] = fmaf(T, C3, acc[11]);
            T *= r;  acc[12] = fmaf(T, C4, acc[12]);
            T *= r;  acc[13] = fmaf(T, C5, acc[13]);
            T *= r;  acc[14] = fmaf(T, C6, acc[14]);
            T *= r;  acc[15] = fmaf(T, C7, acc[15]);
            // down: bins 7..0
            float U = A;
            U *= ri; acc[7] = fmaf(U, C1, acc[7]);
            U *= ri; acc[6] = fmaf(U, C2, acc[6]);
            U *= ri; acc[5] = fmaf(U, C3, acc[5]);
            U *= ri; acc[4] = fmaf(U, C4, acc[4]);
            U *= ri; acc[3] = fmaf(U, C5, acc[3]);
            U *= ri; acc[2] = fmaf(U, C6, acc[2]);
            U *= ri; acc[1] = fmaf(U, C7, acc[1]);
            U *= ri; acc[0] = fmaf(U, C8, acc[0]);
        }
        v = vn;
    }

    // in-wave reduce: bins disjoint across waves -> 16 butterflies, no LDS
    float keep = 0.0f;
    #pragma unroll
    for (int i = 0; i < 16; ++i) {
        float t = acc[i];
        #pragma unroll
        for (int o = 1; o < 64; o <<= 1) t += __shfl_xor(t, o);
        if (lane == i) keep = t;
    }
    if (lane < 16)
        unsafeAtomicAdd(&hist[(tens * NB + batch) * NBINS + kbase + lane], keep);
}

// ---------- pass 3: KL (fp32, v_log), tiny ----------
__global__ __launch_bounds__(256) void final_k(const float* __restrict__ hist,
                                               float* __restrict__ out) {
    const int lane = threadIdx.x & 63, wave = threadIdx.x >> 6;
    __shared__ float wacc[4];
    float a = 0.0f;
    for (int b = wave; b < NB; b += 4) {
        float hp = hist[b * NBINS + lane];
        float ht = hist[(NB + b) * NBINS + lane];
        float sp = hp, st = ht;
        #pragma unroll
        for (int o = 1; o < 64; o <<= 1) {
            sp += __shfl_xor(sp, o);
            st += __shfl_xor(st, o);
        }
        float pp = hp / (sp + EPSF);
        float pt = ht / (st + EPSF);
        float term = pt * ((__builtin_amdgcn_logf(pt + EPSF)
                          - __builtin_amdgcn_logf(pp + EPSF)) * LN2);
        #pragma unroll
        for (int o = 1; o < 64; o <<= 1) term += __shfl_xor(term, o);
        a += term;
    }
    if (lane == 0) wacc[wave] = a;
    __syncthreads();
    if (threadIdx.x == 0)
        out[0] = 0.1f * (wacc[0] + wacc[1] + wacc[2] + wacc[3]) / (float)NB;
}

extern "C" void kernel_launch(void* const* d_in, const int* in_sizes, int n_in,
                              void* d_out, int out_size, void* d_ws, size_t ws_size,
                              hipStream_t stream) {
    const float* pred = (const float*)d_in[0];
    const float* tgt  = (const float*)d_in[1];
    float* mmn  = (float*)d_ws;
    float* mmx  = mmn + NB * MMB;
    float* hist = mmx + NB * MMB;
    float* out  = (float*)d_out;

    minmax_k<<<NB * MMB, 256, 0, stream>>>((const float4*)tgt, mmn, mmx, hist);
    hist_k  <<<2 * NB * CB, 256, 0, stream>>>((const float4*)pred, (const float4*)tgt,
                                              mmn, mmx, hist);
    final_k <<<1, 256, 0, stream>>>(hist, out);
}

// Round 13
// 113.516 us; speedup vs baseline: 1.3389x; 1.0168x over previous
//
#include <hip/hip_runtime.h>
#include <math.h>

// Problem constants
#define NB    16            // batches
#define NPB   (512*512)     // elements per batch
#define NBINS 64
#define MMB   64            // minmax blocks per batch (grid 1024 = 4/CU)
#define CB    64            // hist chunks per (tensor,batch) -> grid 2*16*64 = 2048
#define EPSF  1e-8f
#define QF    0.84932180517f   // sqrt(0.5*log2(e)); exp(-d^2/2) = exp2(-(q*d)^2)
#define L2E   1.44269504089f   // log2(e)
#define LN2   0.69314718056f
#define K16   1.12535175e-7f   // e^-16 (anchor-2 rate adjust)
#define K16I  8886110.5f       // e^+16

// ws layout: mmn[1024] | mmx[1024] | hist[2][16][64]

// ---------- pass 1: per-batch block-level min/max (also zeroes hist) ----------
__global__ __launch_bounds__(256) void minmax_k(const float4* __restrict__ tgt,
                                                float* __restrict__ mmn,
                                                float* __restrict__ mmx,
                                                float* __restrict__ hist) {
    const int batch = blockIdx.x / MMB, sub = blockIdx.x % MMB;
    if (sub == 0 && threadIdx.x < 128) {
        const int tens = threadIdx.x >> 6, lane = threadIdx.x & 63;
        hist[(tens * NB + batch) * NBINS + lane] = 0.0f;
    }

    const int F4 = NPB / 4 / MMB;              // 1024 float4 per block
    const float4* p = tgt + (size_t)batch * (NPB / 4) + (size_t)sub * F4;
    float mn = 3.4e38f, mx = -3.4e38f;
    #pragma unroll
    for (int i = 0; i < F4 / 256; ++i) {       // 4 iterations
        float4 v = p[i * 256 + threadIdx.x];
        mn = fminf(mn, fminf(fminf(v.x, v.y), fminf(v.z, v.w)));
        mx = fmaxf(mx, fmaxf(fmaxf(v.x, v.y), fmaxf(v.z, v.w)));
    }
    #pragma unroll
    for (int o = 1; o < 64; o <<= 1) {
        mn = fminf(mn, __shfl_xor(mn, o));
        mx = fmaxf(mx, __shfl_xor(mx, o));
    }
    __shared__ float smn[4], smx[4];
    const int wave = threadIdx.x >> 6, lane = threadIdx.x & 63;
    if (lane == 0) { smn[wave] = mn; smx[wave] = mx; }
    __syncthreads();
    if (threadIdx.x == 0) {
        mmn[blockIdx.x] = fminf(fminf(smn[0], smn[1]), fminf(smn[2], smn[3]));
        mmx[blockIdx.x] = fmaxf(fmaxf(smx[0], smx[1]), fmaxf(smx[2], smx[3]));
    }
}

// ---------- per-point update of 32 bins via two anchors sharing r/ri ----------
// d = u - (kwbase+8): anchor1 at bin kwbase+8 (covers bins 0..15 of the
// wave's 32), anchor2 at kwbase+24 (covers 16..31), E(m+i) = A * rho^i * C_i
// with C_i = e^{-i^2/2} literals folded into the accumulate FMA.
// rho for anchor2 = r*e^-16 (2 muls; exp2s shared). d clamped to [-30,46]:
// outside, both A==0 before any rho power can overflow (max ~9e19 finite),
// so far points contribute exactly 0 (true contribution < e^-19).
__device__ __forceinline__ void point32(float xin, float s64, float bk8,
                                        float* __restrict__ acc) {
    const float C1 = 0.60653065971f,    C2 = 0.13533528324f,
                C3 = 0.01110899654f,    C4 = 3.35462627903e-4f,
                C5 = 3.72665317208e-6f, C6 = 1.52299797447e-8f,
                C7 = 2.28973484833e-11f, C8 = 1.26641655490e-14f;
    float d   = fmaf(xin, s64, bk8);
    float dc  = __builtin_amdgcn_fmed3f(d, -30.0f, 46.0f);
    float x   = dc * L2E;
    float r   = __builtin_amdgcn_exp2f(x);
    float ri  = __builtin_amdgcn_exp2f(-x);
    float t1  = dc * QF;
    float A1  = __builtin_amdgcn_exp2f(-(t1 * t1));
    float t2  = fmaf(dc, QF, -16.0f * QF);
    float A2  = __builtin_amdgcn_exp2f(-(t2 * t2));
    float r2  = r * K16;
    float ri2 = ri * K16I;
    // anchor1: bins 0..15 (mid 8)
    float T = A1, U = A1;
    acc[8] += A1;
    T *= r;  acc[9]  = fmaf(T, C1, acc[9]);
    T *= r;  acc[10] = fmaf(T, C2, acc[10]);
    T *= r;  acc[11] = fmaf(T, C3, acc[11]);
    T *= r;  acc[12] = fmaf(T, C4, acc[12]);
    T *= r;  acc[13] = fmaf(T, C5, acc[13]);
    T *= r;  acc[14] = fmaf(T, C6, acc[14]);
    T *= r;  acc[15] = fmaf(T, C7, acc[15]);
    U *= ri; acc[7]  = fmaf(U, C1, acc[7]);
    U *= ri; acc[6]  = fmaf(U, C2, acc[6]);
    U *= ri; acc[5]  = fmaf(U, C3, acc[5]);
    U *= ri; acc[4]  = fmaf(U, C4, acc[4]);
    U *= ri; acc[3]  = fmaf(U, C5, acc[3]);
    U *= ri; acc[2]  = fmaf(U, C6, acc[2]);
    U *= ri; acc[1]  = fmaf(U, C7, acc[1]);
    U *= ri; acc[0]  = fmaf(U, C8, acc[0]);
    // anchor2: bins 16..31 (mid 24), rate r2/ri2
    float S = A2, V = A2;
    acc[24] += A2;
    S *= r2;  acc[25] = fmaf(S, C1, acc[25]);
    S *= r2;  acc[26] = fmaf(S, C2, acc[26]);
    S *= r2;  acc[27] = fmaf(S, C3, acc[27]);
    S *= r2;  acc[28] = fmaf(S, C4, acc[28]);
    S *= r2;  acc[29] = fmaf(S, C5, acc[29]);
    S *= r2;  acc[30] = fmaf(S, C6, acc[30]);
    S *= r2;  acc[31] = fmaf(S, C7, acc[31]);
    V *= ri2; acc[23] = fmaf(V, C1, acc[23]);
    V *= ri2; acc[22] = fmaf(V, C2, acc[22]);
    V *= ri2; acc[21] = fmaf(V, C3, acc[21]);
    V *= ri2; acc[20] = fmaf(V, C4, acc[20]);
    V *= ri2; acc[19] = fmaf(V, C5, acc[19]);
    V *= ri2; acc[18] = fmaf(V, C6, acc[18]);
    V *= ri2; acc[17] = fmaf(V, C7, acc[17]);
    V *= ri2; acc[16] = fmaf(V, C8, acc[16]);
}

// ---------- pass 2: gather histogram, 32 bins/wave, wave-pairs split chunk ----
// Waves {0,1} cover bins {0-31, 32-63} on the chunk's first half; waves {2,3}
// the second half -> each point processed 2x (was 4x). 1-deep load prefetch.
// No fence/fused finalize (R8 paradox: per-block fence+atomic serialized
// ~60cyc/block and scaled with grid; fixed in R10).
__global__ __launch_bounds__(256, 4) void hist_k(const float4* __restrict__ pred,
                                                 const float4* __restrict__ tgt,
                                                 const float* __restrict__ mmn,
                                                 const float* __restrict__ mmx,
                                                 float* __restrict__ hist) {
    const int blk   = blockIdx.x;
    const int tens  = blk & 1;
    const int batch = (blk >> 1) & (NB - 1);
    const int chunk = blk >> 5;                      // 0..CB-1
    const int wave  = threadIdx.x >> 6, lane = threadIdx.x & 63;
    const int kwb   = 32 * (wave & 1);               // this wave's first bin
    const int pair  = wave >> 1;                     // which half-chunk

    const int F4C = NPB / 4 / CB;                    // 1024 float4 per chunk
    const int F4H = F4C / 2;                         // 512 per half
    const float4* __restrict__ src = (tens ? tgt : pred)
        + (size_t)batch * (NPB / 4) + (size_t)chunk * F4C + (size_t)pair * F4H;

    // issue first data load before the prologue reduction (overlap)
    float4 v = src[lane];

    // lane-parallel reduce of this batch's 64 minmax partials
    float vmin = mmn[batch * MMB + lane];
    float vmax = mmx[batch * MMB + lane];
    #pragma unroll
    for (int o = 1; o < 64; o <<= 1) {
        vmin = fminf(vmin, __shfl_xor(vmin, o));
        vmax = fmaxf(vmax, __shfl_xor(vmax, o));
    }
    const float s64 = 64.0f / (vmax - vmin + EPSF);
    // d = u - (kwb+8) = x*s64 + bk8
    const float bk8 = fmaf(-vmin, s64, -0.5f) - (float)(kwb + 8);

    float acc[32];
    #pragma unroll
    for (int k = 0; k < 32; ++k) acc[k] = 0.0f;

    const int NIT = F4H / 64;                        // 8 wave-iterations
    #pragma unroll 1
    for (int it = 0; it < NIT; ++it) {
        // prefetch next iteration's data; latency hides under the burst
        float4 vn = src[(it < NIT - 1 ? (it + 1) * 64 : 0) + lane];
        point32(v.x, s64, bk8, acc);
        point32(v.y, s64, bk8, acc);
        point32(v.z, s64, bk8, acc);
        point32(v.w, s64, bk8, acc);
        v = vn;
    }

    // in-wave reduce: 32 butterflies; lane i keeps bin kwb+i
    float keep = 0.0f;
    #pragma unroll
    for (int i = 0; i < 32; ++i) {
        float t = acc[i];
        #pragma unroll
        for (int o = 1; o < 64; o <<= 1) t += __shfl_xor(t, o);
        if (lane == i) keep = t;
    }
    if (lane < 32)
        unsafeAtomicAdd(&hist[(tens * NB + batch) * NBINS + kwb + lane], keep);
}

// ---------- pass 3: KL (fp32, v_log), tiny ----------
__global__ __launch_bounds__(256) void final_k(const float* __restrict__ hist,
                                               float* __restrict__ out) {
    const int lane = threadIdx.x & 63, wave = threadIdx.x >> 6;
    __shared__ float wacc[4];
    float a = 0.0f;
    for (int b = wave; b < NB; b += 4) {
        float hp = hist[b * NBINS + lane];
        float ht = hist[(NB + b) * NBINS + lane];
        float sp = hp, st = ht;
        #pragma unroll
        for (int o = 1; o < 64; o <<= 1) {
            sp += __shfl_xor(sp, o);
            st += __shfl_xor(st, o);
        }
        float pp = hp / (sp + EPSF);
        float pt = ht / (st + EPSF);
        float term = pt * ((__builtin_amdgcn_logf(pt + EPSF)
                          - __builtin_amdgcn_logf(pp + EPSF)) * LN2);
        #pragma unroll
        for (int o = 1; o < 64; o <<= 1) term += __shfl_xor(term, o);
        a += term;
    }
    if (lane == 0) wacc[wave] = a;
    __syncthreads();
    if (threadIdx.x == 0)
        out[0] = 0.1f * (wacc[0] + wacc[1] + wacc[2] + wacc[3]) / (float)NB;
}

extern "C" void kernel_launch(void* const* d_in, const int* in_sizes, int n_in,
                              void* d_out, int out_size, void* d_ws, size_t ws_size,
                              hipStream_t stream) {
    const float* pred = (const float*)d_in[0];
    const float* tgt  = (const float*)d_in[1];
    float* mmn  = (float*)d_ws;
    float* mmx  = mmn + NB * MMB;
    float* hist = mmx + NB * MMB;
    float* out  = (float*)d_out;

    minmax_k<<<NB * MMB, 256, 0, stream>>>((const float4*)tgt, mmn, mmx, hist);
    hist_k  <<<2 * NB * CB, 256, 0, stream>>>((const float4*)pred, (const float4*)tgt,
                                              mmn, mmx, hist);
    final_k <<<1, 256, 0, stream>>>(hist, out);
}